// Round 5
// baseline (713.147 us; speedup 1.0000x reference)
//
#include <hip/hip_runtime.h>
#include <cstdint>

// DynamicExpert: act = topk60(sigmoid(act @ synapse.T)), 2 steps.
// B=8, DIM=8192, fp32. dur_us decomposition across R1-R4 shows ~170 us
// fixed harness poison + gemv ~120-135 us vs ~35 us roofline: DRAM
// pattern-bound (channel camping + 1KB-granular page thrash), NOT
// occupancy (16 vs 32 waves/CU identical). R5: barrier-free gemv with
// 2KB contiguous bursts per row visit + per-block j-rotation to spread
// concurrent accesses over all channels; KPARTS=4 partials combined in
// the topk kernel.

#define DIM 8192
#define BATCH 8
#define KPARTS 4
#define KRANGE (DIM / KPARTS)    // 2048
#define ROWS_PB 16               // W rows per block (4 per wave)
#define NW 4                     // 512-j windows per K-range

// P layout: P[(p*BATCH + b)*DIM + row], 4*8*8192 floats = 1 MB in ws.
// grid: (8192/16)*4 = 2048 blocks x 256 thr (8 blocks/CU, 32 waves/CU,
// VGPR ~80 -> 6 waves/SIMD resident).
__global__ __launch_bounds__(256, 6) void gemv_part(
    const float* __restrict__ A,   // [8][DIM]
    const float* __restrict__ W,   // [DIM][DIM]
    float* __restrict__ P)
{
    const int lane = threadIdx.x & 63;
    const int wid  = threadIdx.x >> 6;
    const int p    = blockIdx.x & (KPARTS - 1);
    const int rg   = blockIdx.x >> 2;             // 0..511
    const int rot  = rg & (NW - 1);               // j-rotation for channel spread
    const int jbeg = p * KRANGE;
    const int row0 = rg * ROWS_PB + wid * 4;      // wave's 4 W rows

    float acc[4][BATCH];
#pragma unroll
    for (int r = 0; r < 4; ++r)
#pragma unroll
        for (int b = 0; b < BATCH; ++b) acc[r][b] = 0.0f;

#pragma unroll 1
    for (int w = 0; w < NW; ++w) {
        const int jw = jbeg + (((w + rot) & (NW - 1)) << 9);  // 512-aligned window

        // 8 W loads issued back-to-back: per row, 2 consecutive float4
        // insts = 2 KB contiguous burst (page-friendly).
        const float* wp = W + (size_t)row0 * DIM + jw + lane * 4;
        float4 wv[4][2];
#pragma unroll
        for (int r = 0; r < 4; ++r) {
            wv[r][0] = *(const float4*)(wp + (size_t)r * DIM);
            wv[r][1] = *(const float4*)(wp + (size_t)r * DIM + 256);
        }

#pragma unroll
        for (int h = 0; h < 2; ++h) {
            const int ja = jw + h * 256 + lane * 4;
#pragma unroll
            for (int b = 0; b < BATCH; ++b) {
                const float4 a = *(const float4*)(A + b * DIM + ja);
#pragma unroll
                for (int r = 0; r < 4; ++r) {
                    acc[r][b] += wv[r][h].x * a.x + wv[r][h].y * a.y
                               + wv[r][h].z * a.z + wv[r][h].w * a.w;
                }
            }
        }
    }

    // reduce 32 sums across the wave; lane 0 stores K-partials
#pragma unroll
    for (int r = 0; r < 4; ++r) {
#pragma unroll
        for (int b = 0; b < BATCH; ++b) {
            float v = acc[r][b];
#pragma unroll
            for (int off = 32; off > 0; off >>= 1)
                v += __shfl_down(v, off, 64);
            if (lane == 0)
                P[(size_t)(p * BATCH + b) * DIM + row0 + r] = v;
        }
    }
}

// Per batch-row block: combine KPARTS partials, sigmoid, top-k sparsify.
// Sigmoid outputs in (0,1): uint bit order == float order. Binary search
// on bit patterns, one __syncthreads per iter (double-buffered counts);
// ties at the cutoff claimed via shared atomic.
__global__ __launch_bounds__(256) void topk_combine(
    const float* __restrict__ P,
    float* __restrict__ Yout,
    const int* __restrict__ kptr)
{
    const int b    = blockIdx.x;     // batch index
    const int tid  = threadIdx.x;
    const int lane = tid & 63;
    const int wid  = tid >> 6;
    int k = kptr ? *kptr : 60;
    if (k > DIM) k = DIM;

    uint32_t v[32];
#pragma unroll
    for (int i = 0; i < 32; ++i) {
        const int idx = tid + i * 256;
        float x = 0.0f;
#pragma unroll
        for (int pp = 0; pp < KPARTS; ++pp)
            x += P[(size_t)(pp * BATCH + b) * DIM + idx];
        v[i] = __float_as_uint(1.0f / (1.0f + __expf(-x)));
    }

    __shared__ int s_part[2][4];
    __shared__ int s_ctr;
    int pb = 0;

    uint32_t lo = 0u, hi = 0x3F800000u;   // (0,1): count(v>=1.0f)=0 < k
    while (hi - lo > 1u) {
        const uint32_t mid = lo + ((hi - lo) >> 1);
        int c = 0;
#pragma unroll
        for (int i = 0; i < 32; ++i) c += (v[i] >= mid) ? 1 : 0;
#pragma unroll
        for (int off = 32; off > 0; off >>= 1)
            c += __shfl_down(c, off, 64);
        if (lane == 0) s_part[pb][wid] = c;
        __syncthreads();
        const int tot = s_part[pb][0] + s_part[pb][1]
                      + s_part[pb][2] + s_part[pb][3];
        pb ^= 1;
        if (tot >= k) lo = mid; else hi = mid;
    }
    const uint32_t cutoff = lo;   // k-th largest value's bits

    int needg;
    {
        int c = 0;
#pragma unroll
        for (int i = 0; i < 32; ++i) c += (v[i] > cutoff) ? 1 : 0;
#pragma unroll
        for (int off = 32; off > 0; off >>= 1)
            c += __shfl_down(c, off, 64);
        if (lane == 0) s_part[pb][wid] = c;
        if (tid == 0) s_ctr = 0;
        __syncthreads();
        needg = s_part[pb][0] + s_part[pb][1]
              + s_part[pb][2] + s_part[pb][3];
    }
    const int need_eq = k - needg;

    float* dst = Yout + (size_t)b * DIM;
#pragma unroll
    for (int i = 0; i < 32; ++i) {
        const uint32_t bits = v[i];
        float val = 0.0f;
        if (bits > cutoff) {
            val = __uint_as_float(bits);
        } else if (bits == cutoff) {
            const int pos = atomicAdd(&s_ctr, 1);
            if (pos < need_eq) val = __uint_as_float(bits);
        }
        dst[tid + i * 256] = val;
    }
}

extern "C" void kernel_launch(void* const* d_in, const int* in_sizes, int n_in,
                              void* d_out, int out_size, void* d_ws, size_t ws_size,
                              hipStream_t stream) {
    const float* sdr = (const float*)d_in[0];
    const float* syn = (const float*)d_in[1];
    const int* kptr  = (n_in > 3) ? (const int*)d_in[3] : nullptr;
    float* out = (float*)d_out;
    float* P   = (float*)d_ws;            // 1 MB of K-partials

    // step 1
    gemv_part<<<(DIM / ROWS_PB) * KPARTS, 256, 0, stream>>>(sdr, syn, P);
    topk_combine<<<BATCH, 256, 0, stream>>>(P, out, kptr);
    // step 2 (input = step-1 sparse activations, dense layout)
    gemv_part<<<(DIM / ROWS_PB) * KPARTS, 256, 0, stream>>>(out, syn, P);
    topk_combine<<<BATCH, 256, 0, stream>>>(P, out, kptr);
}

// Round 6
// 616.343 us; speedup vs baseline: 1.1571x; 1.1571x over previous
//
#include <hip/hip_runtime.h>
#include <cstdint>

// DynamicExpert: act = topk60(sigmoid(act @ synapse.T)), 2 steps.
// B=8, DIM=8192, fp32. W-stream bound. Evidence R3/R5: ~2 TB/s ceiling
// persists even with W in L3 -> latency/MLP-bound, not DRAM. Little's law
// (R3): only ~3 KB avg in flight per CU => per-window vmcnt drain.
// R6: R4's proven no-spill structure (2 rows/wave, K/2 per wave, in-block
// combine) + register software pipeline: issue A(w), then W(w+1), then
// FMA on buffered W(w). FIFO vmcnt keeps the 2 W prefetches in flight
// across every FMA block -> continuous W stream.

#define DIM 8192
#define BATCH 8
#define NWIN ((DIM / 2) / 256)   // 16 windows per K-half

__device__ __forceinline__ float sigmoidf_(float x) {
    return 1.0f / (1.0f + __expf(-x));
}

// grid: 2048 blocks x 256 thr. Block beta owns row-pairs {2b, 2b+1}.
// wave w (0..3): rowpair rp = 2*beta + (w>>1), khalf = w&1.
// VGPR budget: acc 16 + wbuf 8 + wpre 8 + A transients + addr ~= 75.
__global__ __launch_bounds__(256, 6) void gemv8_sigmoid(
    const float* __restrict__ A,
    const float* __restrict__ W,
    float* __restrict__ Y)
{
    const int lane = threadIdx.x & 63;
    const int wid  = threadIdx.x >> 6;
    const int rp   = blockIdx.x * 2 + (wid >> 1);
    const int kh   = wid & 1;
    const int i0   = rp * 2;
    const int jbeg = kh * (DIM / 2);

    float acc0[BATCH], acc1[BATCH];
#pragma unroll
    for (int b = 0; b < BATCH; ++b) { acc0[b] = 0.0f; acc1[b] = 0.0f; }

    const float* wp0 = W + (size_t)i0 * DIM + jbeg + lane * 4;
    const float* wp1 = wp0 + DIM;
    const float* ap  = A + jbeg + lane * 4;

    // prologue: window 0's W
    float4 w0 = *(const float4*)wp0;
    float4 w1 = *(const float4*)wp1;

#pragma unroll 1
    for (int w = 0; w < NWIN - 1; ++w) {
        // issue order matters (vmcnt is FIFO): A(w) first, then W(w+1),
        // so FMAs wait only vmcnt(2) and the W prefetch never drains.
        const float4 a0 = *(const float4*)(ap + 0 * DIM);
        const float4 a1 = *(const float4*)(ap + 1 * DIM);
        const float4 a2 = *(const float4*)(ap + 2 * DIM);
        const float4 a3 = *(const float4*)(ap + 3 * DIM);
        const float4 a4 = *(const float4*)(ap + 4 * DIM);
        const float4 a5 = *(const float4*)(ap + 5 * DIM);
        const float4 a6 = *(const float4*)(ap + 6 * DIM);
        const float4 a7 = *(const float4*)(ap + 7 * DIM);
        wp0 += 256; wp1 += 256;
        const float4 n0 = *(const float4*)wp0;
        const float4 n1 = *(const float4*)wp1;

        acc0[0] += w0.x*a0.x + w0.y*a0.y + w0.z*a0.z + w0.w*a0.w;
        acc1[0] += w1.x*a0.x + w1.y*a0.y + w1.z*a0.z + w1.w*a0.w;
        acc0[1] += w0.x*a1.x + w0.y*a1.y + w0.z*a1.z + w0.w*a1.w;
        acc1[1] += w1.x*a1.x + w1.y*a1.y + w1.z*a1.z + w1.w*a1.w;
        acc0[2] += w0.x*a2.x + w0.y*a2.y + w0.z*a2.z + w0.w*a2.w;
        acc1[2] += w1.x*a2.x + w1.y*a2.y + w1.z*a2.z + w1.w*a2.w;
        acc0[3] += w0.x*a3.x + w0.y*a3.y + w0.z*a3.z + w0.w*a3.w;
        acc1[3] += w1.x*a3.x + w1.y*a3.y + w1.z*a3.z + w1.w*a3.w;
        acc0[4] += w0.x*a4.x + w0.y*a4.y + w0.z*a4.z + w0.w*a4.w;
        acc1[4] += w1.x*a4.x + w1.y*a4.y + w1.z*a4.z + w1.w*a4.w;
        acc0[5] += w0.x*a5.x + w0.y*a5.y + w0.z*a5.z + w0.w*a5.w;
        acc1[5] += w1.x*a5.x + w1.y*a5.y + w1.z*a5.z + w1.w*a5.w;
        acc0[6] += w0.x*a6.x + w0.y*a6.y + w0.z*a6.z + w0.w*a6.w;
        acc1[6] += w1.x*a6.x + w1.y*a6.y + w1.z*a6.z + w1.w*a6.w;
        acc0[7] += w0.x*a7.x + w0.y*a7.y + w0.z*a7.z + w0.w*a7.w;
        acc1[7] += w1.x*a7.x + w1.y*a7.y + w1.z*a7.z + w1.w*a7.w;

        w0 = n0; w1 = n1;
        ap += 256;
    }

    // epilogue: last window
    {
#pragma unroll
        for (int b = 0; b < BATCH; ++b) {
            const float4 a = *(const float4*)(ap + (size_t)b * DIM);
            acc0[b] += w0.x*a.x + w0.y*a.y + w0.z*a.z + w0.w*a.w;
            acc1[b] += w1.x*a.x + w1.y*a.y + w1.z*a.z + w1.w*a.w;
        }
    }

    // reduce 16 sums across the wave; lane 0 -> LDS partials
    __shared__ float part[2][2][2][BATCH];   // [rp_in_blk][khalf][row][b]
#pragma unroll
    for (int b = 0; b < BATCH; ++b) {
        float v0 = acc0[b], v1 = acc1[b];
#pragma unroll
        for (int off = 32; off > 0; off >>= 1) {
            v0 += __shfl_down(v0, off, 64);
            v1 += __shfl_down(v1, off, 64);
        }
        if (lane == 0) {
            part[wid >> 1][kh][0][b] = v0;
            part[wid >> 1][kh][1][b] = v1;
        }
    }
    __syncthreads();

    // combine K-halves, sigmoid, store: 32 outputs (2 rp x 2 rows x 8 b)
    if (threadIdx.x < 32) {
        const int b = threadIdx.x & 7;
        const int r = (threadIdx.x >> 3) & 1;
        const int q = threadIdx.x >> 4;
        const float s = part[q][0][r][b] + part[q][1][r][b];
        const int row = (blockIdx.x * 2 + q) * 2 + r;
        Y[b * DIM + row] = sigmoidf_(s);
    }
}

// Per row (block): keep top-k values, zero the rest. Sigmoid outputs in
// (0,1): uint bit order == float order. Row in 32 regs/thread; binary
// search on bit patterns, one __syncthreads per iter (double-buffered
// counts); ties claimed via shared atomic. In-place safe: all loads
// complete before the first __syncthreads().
__global__ __launch_bounds__(256) void topk_sparsify(
    const float* __restrict__ Yin,
    float* __restrict__ Yout,
    const int* __restrict__ kptr)
{
    const int row  = blockIdx.x;
    const int tid  = threadIdx.x;
    const int lane = tid & 63;
    const int wid  = tid >> 6;
    int k = kptr ? *kptr : 60;
    if (k > DIM) k = DIM;

    uint32_t v[32];
    const float* src = Yin + (size_t)row * DIM;
#pragma unroll
    for (int i = 0; i < 32; ++i)
        v[i] = __float_as_uint(src[tid + i * 256]);

    __shared__ int s_part[2][4];
    __shared__ int s_ctr;
    int pb = 0;

    uint32_t lo = 0u, hi = 0x3F800000u;   // (0,1): count(v>=1.0f)=0 < k
    while (hi - lo > 1u) {
        const uint32_t mid = lo + ((hi - lo) >> 1);
        int c = 0;
#pragma unroll
        for (int i = 0; i < 32; ++i) c += (v[i] >= mid) ? 1 : 0;
#pragma unroll
        for (int off = 32; off > 0; off >>= 1)
            c += __shfl_down(c, off, 64);
        if (lane == 0) s_part[pb][wid] = c;
        __syncthreads();
        const int tot = s_part[pb][0] + s_part[pb][1]
                      + s_part[pb][2] + s_part[pb][3];
        pb ^= 1;
        if (tot >= k) lo = mid; else hi = mid;
    }
    const uint32_t cutoff = lo;

    int needg;
    {
        int c = 0;
#pragma unroll
        for (int i = 0; i < 32; ++i) c += (v[i] > cutoff) ? 1 : 0;
#pragma unroll
        for (int off = 32; off > 0; off >>= 1)
            c += __shfl_down(c, off, 64);
        if (lane == 0) s_part[pb][wid] = c;
        if (tid == 0) s_ctr = 0;
        __syncthreads();
        needg = s_part[pb][0] + s_part[pb][1]
              + s_part[pb][2] + s_part[pb][3];
    }
    const int need_eq = k - needg;

    float* dst = Yout + (size_t)row * DIM;
#pragma unroll
    for (int i = 0; i < 32; ++i) {
        const uint32_t b = v[i];
        float val = 0.0f;
        if (b > cutoff) {
            val = __uint_as_float(b);
        } else if (b == cutoff) {
            const int pos = atomicAdd(&s_ctr, 1);
            if (pos < need_eq) val = __uint_as_float(b);
        }
        dst[tid + i * 256] = val;
    }
}

extern "C" void kernel_launch(void* const* d_in, const int* in_sizes, int n_in,
                              void* d_out, int out_size, void* d_ws, size_t ws_size,
                              hipStream_t stream) {
    const float* sdr = (const float*)d_in[0];
    const float* syn = (const float*)d_in[1];
    const int* kptr  = (n_in > 3) ? (const int*)d_in[3] : nullptr;
    float* out = (float*)d_out;
    float* tmp = (float*)d_ws;            // 256 KB scratch

    // step 1: y = sigmoid(sdr @ W^T) -> d_out, sparsify in place
    gemv8_sigmoid<<<2048, 256, 0, stream>>>(sdr, syn, out);
    topk_sparsify<<<8, 256, 0, stream>>>(out, out, kptr);
    // step 2: y = sigmoid(act1 @ W^T) -> ws, sparsify -> d_out
    gemv8_sigmoid<<<2048, 256, 0, stream>>>(out, syn, tmp);
    topk_sparsify<<<8, 256, 0, stream>>>(tmp, out, kptr);
}

// Round 7
// 509.755 us; speedup vs baseline: 1.3990x; 1.2091x over previous
//
#include <hip/hip_runtime.h>
#include <cstdint>

// DynamicExpert: act = topk60(sigmoid(act @ synapse.T)), 2 steps.
// B=8, DIM=8192, fp32. W-stream latency/MLP-bound (~7 KB in flight/CU
// measured via Little's law). R7: (a) amdgpu_waves_per_eu(4,4) forces a
// 128-VGPR budget -- kills the allocator's 40-reg spill heuristic that
// destroyed R5/R6; (b) 4 rows/wave + cross-window register pipeline:
// issue A(w) then W(w+1), FMA on buffered W(w); FIFO vmcnt keeps the 4
// W prefetches in flight across every FMA block. KPARTS=4 -> 2048 blocks,
// partial sums combined in the fused sigmoid+topk kernel.

#define DIM 8192
#define BATCH 8
#define KPARTS 4
#define KRANGE (DIM / KPARTS)    // 2048
#define ROWS_PB 16               // 4 waves x 4 rows
#define NWIN (KRANGE / 256)      // 8 windows per K-part

#define DOT(c, a) ((c).x*(a).x + (c).y*(a).y + (c).z*(a).z + (c).w*(a).w)

// P layout: P[(p*BATCH + b)*DIM + row], 4*8*8192 floats = 1 MB in ws.
// grid: 512 row-groups x 4 K-parts = 2048 blocks x 256 thr.
__global__ void __launch_bounds__(256)
__attribute__((amdgpu_waves_per_eu(4, 4)))
gemv_part(
    const float* __restrict__ A,   // [8][DIM]
    const float* __restrict__ W,   // [DIM][DIM]
    float* __restrict__ P)
{
    const int lane = threadIdx.x & 63;
    const int wid  = threadIdx.x >> 6;
    const int p    = blockIdx.x & (KPARTS - 1);
    const int rg   = blockIdx.x >> 2;             // 0..511
    const int jbeg = p * KRANGE;
    const int row0 = rg * ROWS_PB + wid * 4;      // wave's 4 W rows

    float acc[4][BATCH];
#pragma unroll
    for (int r = 0; r < 4; ++r)
#pragma unroll
        for (int b = 0; b < BATCH; ++b) acc[r][b] = 0.0f;

    const float* wp = W + (size_t)row0 * DIM + jbeg + lane * 4;
    const float* ap = A + jbeg + lane * 4;

    // prologue: window 0's W rows
    float4 c0 = *(const float4*)(wp + 0 * (size_t)DIM);
    float4 c1 = *(const float4*)(wp + 1 * (size_t)DIM);
    float4 c2 = *(const float4*)(wp + 2 * (size_t)DIM);
    float4 c3 = *(const float4*)(wp + 3 * (size_t)DIM);

#pragma unroll 1
    for (int w = 0; w < NWIN - 1; ++w) {
        // A(w) first, then W(w+1): FIFO vmcnt lets FMAs wait only on A
        // while the W prefetch stays outstanding.
        const float4 a0 = *(const float4*)(ap + 0 * (size_t)DIM);
        const float4 a1 = *(const float4*)(ap + 1 * (size_t)DIM);
        const float4 a2 = *(const float4*)(ap + 2 * (size_t)DIM);
        const float4 a3 = *(const float4*)(ap + 3 * (size_t)DIM);
        const float4 a4 = *(const float4*)(ap + 4 * (size_t)DIM);
        const float4 a5 = *(const float4*)(ap + 5 * (size_t)DIM);
        const float4 a6 = *(const float4*)(ap + 6 * (size_t)DIM);
        const float4 a7 = *(const float4*)(ap + 7 * (size_t)DIM);
        wp += 256;
        const float4 n0 = *(const float4*)(wp + 0 * (size_t)DIM);
        const float4 n1 = *(const float4*)(wp + 1 * (size_t)DIM);
        const float4 n2 = *(const float4*)(wp + 2 * (size_t)DIM);
        const float4 n3 = *(const float4*)(wp + 3 * (size_t)DIM);

        acc[0][0] += DOT(c0, a0); acc[1][0] += DOT(c1, a0);
        acc[2][0] += DOT(c2, a0); acc[3][0] += DOT(c3, a0);
        acc[0][1] += DOT(c0, a1); acc[1][1] += DOT(c1, a1);
        acc[2][1] += DOT(c2, a1); acc[3][1] += DOT(c3, a1);
        acc[0][2] += DOT(c0, a2); acc[1][2] += DOT(c1, a2);
        acc[2][2] += DOT(c2, a2); acc[3][2] += DOT(c3, a2);
        acc[0][3] += DOT(c0, a3); acc[1][3] += DOT(c1, a3);
        acc[2][3] += DOT(c2, a3); acc[3][3] += DOT(c3, a3);
        acc[0][4] += DOT(c0, a4); acc[1][4] += DOT(c1, a4);
        acc[2][4] += DOT(c2, a4); acc[3][4] += DOT(c3, a4);
        acc[0][5] += DOT(c0, a5); acc[1][5] += DOT(c1, a5);
        acc[2][5] += DOT(c2, a5); acc[3][5] += DOT(c3, a5);
        acc[0][6] += DOT(c0, a6); acc[1][6] += DOT(c1, a6);
        acc[2][6] += DOT(c2, a6); acc[3][6] += DOT(c3, a6);
        acc[0][7] += DOT(c0, a7); acc[1][7] += DOT(c1, a7);
        acc[2][7] += DOT(c2, a7); acc[3][7] += DOT(c3, a7);

        c0 = n0; c1 = n1; c2 = n2; c3 = n3;
        ap += 256;
    }

    // epilogue: last window
    {
        const float4 a0 = *(const float4*)(ap + 0 * (size_t)DIM);
        const float4 a1 = *(const float4*)(ap + 1 * (size_t)DIM);
        const float4 a2 = *(const float4*)(ap + 2 * (size_t)DIM);
        const float4 a3 = *(const float4*)(ap + 3 * (size_t)DIM);
        const float4 a4 = *(const float4*)(ap + 4 * (size_t)DIM);
        const float4 a5 = *(const float4*)(ap + 5 * (size_t)DIM);
        const float4 a6 = *(const float4*)(ap + 6 * (size_t)DIM);
        const float4 a7 = *(const float4*)(ap + 7 * (size_t)DIM);
        acc[0][0] += DOT(c0, a0); acc[1][0] += DOT(c1, a0);
        acc[2][0] += DOT(c2, a0); acc[3][0] += DOT(c3, a0);
        acc[0][1] += DOT(c0, a1); acc[1][1] += DOT(c1, a1);
        acc[2][1] += DOT(c2, a1); acc[3][1] += DOT(c3, a1);
        acc[0][2] += DOT(c0, a2); acc[1][2] += DOT(c1, a2);
        acc[2][2] += DOT(c2, a2); acc[3][2] += DOT(c3, a2);
        acc[0][3] += DOT(c0, a3); acc[1][3] += DOT(c1, a3);
        acc[2][3] += DOT(c2, a3); acc[3][3] += DOT(c3, a3);
        acc[0][4] += DOT(c0, a4); acc[1][4] += DOT(c1, a4);
        acc[2][4] += DOT(c2, a4); acc[3][4] += DOT(c3, a4);
        acc[0][5] += DOT(c0, a5); acc[1][5] += DOT(c1, a5);
        acc[2][5] += DOT(c2, a5); acc[3][5] += DOT(c3, a5);
        acc[0][6] += DOT(c0, a6); acc[1][6] += DOT(c1, a6);
        acc[2][6] += DOT(c2, a6); acc[3][6] += DOT(c3, a6);
        acc[0][7] += DOT(c0, a7); acc[1][7] += DOT(c1, a7);
        acc[2][7] += DOT(c2, a7); acc[3][7] += DOT(c3, a7);
    }

    // reduce 32 sums across the wave; lane 0 stores K-partials
#pragma unroll
    for (int r = 0; r < 4; ++r) {
#pragma unroll
        for (int b = 0; b < BATCH; ++b) {
            float v = acc[r][b];
#pragma unroll
            for (int off = 32; off > 0; off >>= 1)
                v += __shfl_down(v, off, 64);
            if (lane == 0)
                P[(size_t)(p * BATCH + b) * DIM + row0 + r] = v;
        }
    }
}

// Per batch-row block: combine KPARTS partials, sigmoid, top-k sparsify.
// Sigmoid outputs in (0,1): uint bit order == float order. Binary search
// on bit patterns, one __syncthreads per iter (double-buffered counts);
// ties at the cutoff claimed via shared atomic.
__global__ __launch_bounds__(256) void topk_combine(
    const float* __restrict__ P,
    float* __restrict__ Yout,
    const int* __restrict__ kptr)
{
    const int b    = blockIdx.x;     // batch index
    const int tid  = threadIdx.x;
    const int lane = tid & 63;
    const int wid  = tid >> 6;
    int k = kptr ? *kptr : 60;
    if (k > DIM) k = DIM;

    uint32_t v[32];
#pragma unroll
    for (int i = 0; i < 32; ++i) {
        const int idx = tid + i * 256;
        float x = 0.0f;
#pragma unroll
        for (int pp = 0; pp < KPARTS; ++pp)
            x += P[(size_t)(pp * BATCH + b) * DIM + idx];
        v[i] = __float_as_uint(1.0f / (1.0f + __expf(-x)));
    }

    __shared__ int s_part[2][4];
    __shared__ int s_ctr;
    int pb = 0;

    uint32_t lo = 0u, hi = 0x3F800000u;   // (0,1): count(v>=1.0f)=0 < k
    while (hi - lo > 1u) {
        const uint32_t mid = lo + ((hi - lo) >> 1);
        int c = 0;
#pragma unroll
        for (int i = 0; i < 32; ++i) c += (v[i] >= mid) ? 1 : 0;
#pragma unroll
        for (int off = 32; off > 0; off >>= 1)
            c += __shfl_down(c, off, 64);
        if (lane == 0) s_part[pb][wid] = c;
        __syncthreads();
        const int tot = s_part[pb][0] + s_part[pb][1]
                      + s_part[pb][2] + s_part[pb][3];
        pb ^= 1;
        if (tot >= k) lo = mid; else hi = mid;
    }
    const uint32_t cutoff = lo;   // k-th largest value's bits

    int needg;
    {
        int c = 0;
#pragma unroll
        for (int i = 0; i < 32; ++i) c += (v[i] > cutoff) ? 1 : 0;
#pragma unroll
        for (int off = 32; off > 0; off >>= 1)
            c += __shfl_down(c, off, 64);
        if (lane == 0) s_part[pb][wid] = c;
        if (tid == 0) s_ctr = 0;
        __syncthreads();
        needg = s_part[pb][0] + s_part[pb][1]
              + s_part[pb][2] + s_part[pb][3];
    }
    const int need_eq = k - needg;

    float* dst = Yout + (size_t)b * DIM;
#pragma unroll
    for (int i = 0; i < 32; ++i) {
        const uint32_t bits = v[i];
        float val = 0.0f;
        if (bits > cutoff) {
            val = __uint_as_float(bits);
        } else if (bits == cutoff) {
            const int pos = atomicAdd(&s_ctr, 1);
            if (pos < need_eq) val = __uint_as_float(bits);
        }
        dst[tid + i * 256] = val;
    }
}

extern "C" void kernel_launch(void* const* d_in, const int* in_sizes, int n_in,
                              void* d_out, int out_size, void* d_ws, size_t ws_size,
                              hipStream_t stream) {
    const float* sdr = (const float*)d_in[0];
    const float* syn = (const float*)d_in[1];
    const int* kptr  = (n_in > 3) ? (const int*)d_in[3] : nullptr;
    float* out = (float*)d_out;
    float* P   = (float*)d_ws;            // 1 MB of K-partials

    // step 1
    gemv_part<<<(DIM / ROWS_PB) * KPARTS, 256, 0, stream>>>(sdr, syn, P);
    topk_combine<<<BATCH, 256, 0, stream>>>(P, out, kptr);
    // step 2 (input = step-1 sparse activations, dense layout)
    gemv_part<<<(DIM / ROWS_PB) * KPARTS, 256, 0, stream>>>(out, syn, P);
    topk_combine<<<BATCH, 256, 0, stream>>>(P, out, kptr);
}